// Round 6
// baseline (138.859 us; speedup 1.0000x reference)
//
#include <hip/hip_runtime.h>
#include <math.h>

#define B_    8
#define S_    128
#define K_    12
#define DAR_  256
#define DENC_ 256
#define NNEG_ 128
#define W_    116          // S - K
#define BW_   928          // B * W
#define HBW_  464          // BW / 2

typedef __attribute__((ext_vector_type(8))) short short8;   // 8 bf16 (4 VGPRs)
typedef __attribute__((ext_vector_type(4))) float floatx4;  // MFMA C/D

static __device__ __forceinline__ unsigned short f2bf(float f) {
    union { float f; unsigned int u; } v; v.f = f;
    return (unsigned short)((v.u + 0x7FFFu + ((v.u >> 16) & 1u)) >> 16);  // RNE
}

static __device__ __forceinline__ uint4 pack8(const float* p) {
    float4 v0 = *(const float4*)p;
    float4 v1 = *(const float4*)(p + 4);
    uint4 o;
    o.x = f2bf(v0.x) | ((unsigned)f2bf(v0.y) << 16);
    o.y = f2bf(v0.z) | ((unsigned)f2bf(v0.w) << 16);
    o.z = f2bf(v1.x) | ((unsigned)f2bf(v1.y) << 16);
    o.w = f2bf(v1.z) | ((unsigned)f2bf(v1.w) << 16);
    return o;
}

// ---------------------------------------------------------------------------
// Stage 1 (MFMA, fp32 inputs packed in-register): locC[k][bw][e] bf16.
// MEASUREMENT ROUND: grid z = 36 -> each k-tile computed 3x (idempotent,
// same values written). Surfaces stage1's counters above the 42us fills.
// Grid (16,4,36): x<15 compute; x==15 -> enc cast (also idempotent).
// ---------------------------------------------------------------------------
__global__ __launch_bounds__(256) void stage1_mfma(
    const float* __restrict__ cFeat,   // (B,S,256) fp32
    const float* __restrict__ Wp,      // (K,256,256) fp32
    const float* __restrict__ enc,     // (B,S,256) fp32
    unsigned short* __restrict__ ench, // (B,S,256) bf16 out
    unsigned short* __restrict__ locCh)// (K,BW,256) bf16 out
{
    const int tid = threadIdx.x;
    const int k  = blockIdx.z % K_;           // 3 reps of each k

    if (blockIdx.x == 15) {            // ---- enc cast (3x idempotent) ----
        const int cb = (blockIdx.z % K_) * 4 + blockIdx.y;   // 0..47
#pragma unroll
        for (int i = 0; i < 3; ++i) {
            const int c = cb * 768 + i * 256 + tid;          // 8-float chunks
            if (c < 32768)
                *(uint4*)(ench + c * 8) = pack8(enc + c * 8);
        }
        return;
    }

    __shared__ unsigned short Bh[64 * 256];   // 32 KB, swizzled

    const int mt = blockIdx.x;                // 0..14 bw-tiles (last partial)
    const int nt = blockIdx.y;                // 4 e-tiles

    const int lane = tid & 63, wv = tid >> 6;
    const int l15 = lane & 15, quad = lane >> 4;

    // ---- A fragments direct from global fp32, packed to bf16 ----
    const int am = mt * 64 + wv * 16 + l15;   // bw row
    short8 a[8];
    if (am < BW_) {
        const int b = am / W_, w = am - b * W_;
        const float* arow = cFeat + (size_t)(b * S_ + w) * 256;
#pragma unroll
        for (int kt = 0; kt < 8; ++kt) {
            uint4 p = pack8(arow + kt * 32 + quad * 8);
            a[kt] = *(short8*)&p;
        }
    } else {
#pragma unroll
        for (int kt = 0; kt < 8; ++kt) a[kt] = short8{0,0,0,0,0,0,0,0};
    }

    // ---- B staging: 64 rows x 32 chunks, fp32->bf16, swizzled ----
#pragma unroll
    for (int i = 0; i < 8; ++i) {
        const int flat = i * 256 + tid;
        const int row = flat >> 5, ch = flat & 31;
        const int e = nt * 64 + row;
        uint4 bv = pack8(Wp + ((size_t)(k * 256 + e) * 256 + ch * 8));
        *(uint4*)&Bh[(row * 32 + (ch ^ (row & 7))) * 8] = bv;
    }
    __syncthreads();

    floatx4 acc[4];
#pragma unroll
    for (int n4 = 0; n4 < 4; ++n4) {
        floatx4 c = {0.f, 0.f, 0.f, 0.f};
        const int bn = n4 * 16 + l15;
#pragma unroll
        for (int kt = 0; kt < 8; ++kt) {
            const int ch = kt * 4 + quad;
            short8 bfrag = *(const short8*)&Bh[(bn * 32 + (ch ^ (bn & 7))) * 8];
            c = __builtin_amdgcn_mfma_f32_16x16x32_bf16(a[kt], bfrag, c, 0, 0, 0);
        }
        acc[n4] = c;
    }

    // D: col(e)=l15, row(bw)=quad*4+r within subtile
#pragma unroll
    for (int n4 = 0; n4 < 4; ++n4) {
        const int e = nt * 64 + n4 * 16 + l15;
#pragma unroll
        for (int r = 0; r < 4; ++r) {
            const int bwo = mt * 64 + wv * 16 + quad * 4 + r;
            if (bwo < BW_)
                locCh[((size_t)k * BW_ + bwo) * 256 + e] = f2bf(acc[n4][r]);
        }
    }
}

// ---------------------------------------------------------------------------
// Stage 2 (MFMA): block handles TWO (b,w) pairs (bw, bw+464).
// MEASUREMENT ROUND: grid y = 3 -> three reps, each writing its own part
// buffer (rep 0 is the real one). Surfaces stage2's counters.
// ---------------------------------------------------------------------------
__global__ __launch_bounds__(256) void stage2_mfma(
    const unsigned short* __restrict__ ench,   // (B,S,256) bf16
    const unsigned short* __restrict__ locCh,  // (K,BW,256) bf16
    const int* __restrict__ batchIdx,
    const int* __restrict__ seqIdx,
    float* __restrict__ part0)                 // 3 x (2K, BW)
{
    __shared__ int   idxL[2][144];
    __shared__ float sc[2][K_ * 132];   // [0..127]=neg, [128]=pos

    float* part = part0 + blockIdx.y * (2 * K_ * BW_);

    const int tid = threadIdx.x;
    const int lane = tid & 63, wv = tid >> 6;
    const int l15 = lane & 15, quad = lane >> 4;

    int bwp[2], bp[2], wp[2];
#pragma unroll
    for (int pr = 0; pr < 2; ++pr) {
        bwp[pr] = blockIdx.x + pr * HBW_;
        bp[pr] = bwp[pr] / W_;
        wp[pr] = bwp[pr] - bp[pr] * W_;
    }

    // ---- indices: threads 0..127 -> pair0 negs, 128..255 -> pair1 negs ----
    {
        const int pr = tid >> 7, n = tid & 127;
        const int ii = (bp[pr] * NNEG_ + n) * W_ + wp[pr];
        const int bi = batchIdx[ii];
        int si = seqIdx[ii] + wp[pr];          // seqIdx in [1,S), w<=115 -> <243
        if (si >= S_) si -= S_;
        idxL[pr][n] = bi * S_ + si;
    }
    if (tid < 24) {                            // positives
        const int pr = tid / K_, kk = tid - pr * K_;
        idxL[pr][128 + kk] = bp[pr] * S_ + wp[pr] + 1 + kk;
    }

    // ---- A fragments (both pairs) direct from global ----
    const int m = (l15 < K_) ? l15 : (K_ - 1);
    short8 a[2][8];
#pragma unroll
    for (int pr = 0; pr < 2; ++pr) {
        const unsigned short* arow = locCh + ((size_t)m * BW_ + bwp[pr]) * 256;
#pragma unroll
        for (int kt = 0; kt < 8; ++kt)
            a[pr][kt] = *(const short8*)(arow + kt * 32 + quad * 8);
    }
    __syncthreads();

    // ---- 9 N-tiles over 4 waves, both pairs interleaved ----
    floatx4 accT[2][3];
#pragma unroll
    for (int u = 0; u < 3; ++u) {
        const int t = wv + u * 4;
#pragma unroll
        for (int pr = 0; pr < 2; ++pr) {
            floatx4 c = {0.f, 0.f, 0.f, 0.f};
            if (t < 9) {
                const int n = t * 16 + l15;
                const int nn = (n < 140) ? n : 128;
                const unsigned short* brow = ench + (size_t)idxL[pr][nn] * 256;
#pragma unroll
                for (int kt = 0; kt < 8; ++kt) {
                    short8 bfrag = *(const short8*)(brow + kt * 32 + quad * 8);
                    c = __builtin_amdgcn_mfma_f32_16x16x32_bf16(a[pr][kt], bfrag, c, 0, 0, 0);
                }
            }
            accT[pr][u] = c;
        }
    }

    const float inv = 1.0f / 256.0f;
#pragma unroll
    for (int u = 0; u < 3; ++u) {
        const int t = wv + u * 4;
        if (t < 9) {
#pragma unroll
            for (int pr = 0; pr < 2; ++pr) {
#pragma unroll
                for (int r = 0; r < 4; ++r) {
                    const int mm = quad * 4 + r;       // accumulator row = k
                    if (mm < K_) {
                        const float val = accT[pr][u][r] * inv;
                        if (t < 8)           sc[pr][mm * 132 + t * 16 + l15] = val;
                        else if (l15 == mm)  sc[pr][mm * 132 + 128] = val;
                    }
                }
            }
        }
    }
    __syncthreads();

    // ---- LSE + acc per k, both pairs (wave wv: k = wv, wv+4, wv+8) ----
    for (int k = wv; k < K_; k += 4) {
#pragma unroll
        for (int pr = 0; pr < 2; ++pr) {
            const float x0  = sc[pr][k * 132 + lane];
            const float x1  = sc[pr][k * 132 + 64 + lane];
            const float pos = sc[pr][k * 132 + 128];
            float mn = fmaxf(x0, x1);
#pragma unroll
            for (int o = 1; o < 64; o <<= 1) mn = fmaxf(mn, __shfl_xor(mn, o, 64));
            const float m2 = fmaxf(mn, pos);
            float s = __expf(x0 - m2) + __expf(x1 - m2);
#pragma unroll
            for (int o = 1; o < 64; o <<= 1) s += __shfl_xor(s, o, 64);
            if (lane == 0) {
                const float lse = m2 + __logf(s + __expf(pos - m2));
                part[k * BW_ + bwp[pr]]        = lse - pos;
                part[(K_ + k) * BW_ + bwp[pr]] = (pos >= mn) ? 1.0f : 0.0f;
            }
        }
    }
}

// ---------------------------------------------------------------------------
// Stage 3: reduce (2K, BW) partials (rep 0) to the 24 outputs.
// ---------------------------------------------------------------------------
__global__ __launch_bounds__(256) void stage3_reduce(
    const float* __restrict__ part, float* __restrict__ out)
{
    __shared__ float wsum[4];
    const int o = blockIdx.x, tid = threadIdx.x;
    float s = 0.f;
    for (int i = tid; i < BW_; i += 256) s += part[o * BW_ + i];
#pragma unroll
    for (int off = 1; off < 64; off <<= 1) s += __shfl_xor(s, off, 64);
    if ((tid & 63) == 0) wsum[tid >> 6] = s;
    __syncthreads();
    if (tid == 0)
        out[o] = (wsum[0] + wsum[1] + wsum[2] + wsum[3]) / (float)BW_;
}

// ---------------------------------------------------------------------------
extern "C" void kernel_launch(void* const* d_in, const int* in_sizes, int n_in,
                              void* d_out, int out_size, void* d_ws, size_t ws_size,
                              hipStream_t stream) {
    const float* cFeat    = (const float*)d_in[0];
    const float* enc      = (const float*)d_in[1];
    const float* Wp       = (const float*)d_in[2];
    const int*   batchIdx = (const int*)d_in[3];
    const int*   seqIdx   = (const int*)d_in[4];
    float* out = (float*)d_out;

    unsigned short* ench  = (unsigned short*)d_ws;            // 262144 bf16
    unsigned short* locCh = ench + 262144;                    // K*BW*256 bf16
    float* part = (float*)(locCh + (size_t)K_ * BW_ * 256);   // 3 x (2K,BW)

    // Amplified x3 dispatches (idempotent / private-scratch): makes stage1 and
    // stage2 each exceed the 42us fills so their counter rows surface in top-5.
    hipLaunchKernelGGL(stage1_mfma, dim3(16, 4, 36), dim3(256), 0, stream,
                       cFeat, Wp, enc, ench, locCh);
    hipLaunchKernelGGL(stage2_mfma, dim3(HBW_, 3), dim3(256), 0, stream,
                       ench, locCh, batchIdx, seqIdx, part);
    hipLaunchKernelGGL(stage3_reduce, dim3(24), dim3(256), 0, stream,
                       part, out);
}

// Round 7
// 101.684 us; speedup vs baseline: 1.3656x; 1.3656x over previous
//
#include <hip/hip_runtime.h>
#include <math.h>

#define B_    8
#define S_    128
#define K_    12
#define DAR_  256
#define DENC_ 256
#define NNEG_ 128
#define W_    116          // S - K
#define BW_   928          // B * W
#define NIDX_ 118784       // NNEG * W * B

typedef __attribute__((ext_vector_type(8))) short short8;   // 8 bf16 (4 VGPRs)
typedef __attribute__((ext_vector_type(4))) float floatx4;  // MFMA C/D

static __device__ __forceinline__ unsigned short f2bf(float f) {
    union { float f; unsigned int u; } v; v.f = f;
    return (unsigned short)((v.u + 0x7FFFu + ((v.u >> 16) & 1u)) >> 16);  // RNE
}

static __device__ __forceinline__ uint4 pack8(const float* p) {
    float4 v0 = *(const float4*)p;
    float4 v1 = *(const float4*)(p + 4);
    uint4 o;
    o.x = f2bf(v0.x) | ((unsigned)f2bf(v0.y) << 16);
    o.y = f2bf(v0.z) | ((unsigned)f2bf(v0.w) << 16);
    o.z = f2bf(v1.x) | ((unsigned)f2bf(v1.y) << 16);
    o.w = f2bf(v1.z) | ((unsigned)f2bf(v1.w) << 16);
    return o;
}

// ---------------------------------------------------------------------------
// Stage 1: grid (16, 8, 12). x<15: 64(bw) x 32(e) MFMA tile (1440 blocks ->
// 5.6/CU for more cold-miss streams). x==15: 96 aux blocks cast enc->bf16 AND
// precompute idxT (overlaps the scattered idx cold misses with the GEMM).
// ---------------------------------------------------------------------------
__global__ __launch_bounds__(256) void stage1_mfma(
    const float* __restrict__ cFeat,   // (B,S,256) fp32
    const float* __restrict__ Wp,      // (K,256,256) fp32
    const float* __restrict__ enc,     // (B,S,256) fp32
    const int* __restrict__ batchIdx,
    const int* __restrict__ seqIdx,
    unsigned short* __restrict__ ench, // (B,S,256) bf16 out
    unsigned short* __restrict__ locCh,// (K,BW,256) bf16 out
    int* __restrict__ idxT)            // (BW, 128) gather rows
{
    const int tid = threadIdx.x;

    if (blockIdx.x == 15) {            // ---- aux: cast + idx table ----
        const int ab = blockIdx.z * 8 + blockIdx.y;        // 0..95
        for (int c = ab * 256 + tid; c < 32768; c += 96 * 256)
            *(uint4*)(ench + c * 8) = pack8(enc + c * 8);
        // idxT[j], j = bw*128 + n  (coalesced writes, scattered reads)
        for (int j = ab * 256 + tid; j < NIDX_; j += 96 * 256) {
            const int n = j & 127, bw = j >> 7;
            const int b = bw / W_, w = bw - b * W_;
            const int ii = (b * NNEG_ + n) * W_ + w;
            const int bi = batchIdx[ii];
            int si = seqIdx[ii] + w;               // < 243
            if (si >= S_) si -= S_;
            idxT[j] = bi * S_ + si;
        }
        return;
    }

    __shared__ unsigned short Bh[32 * 256];   // 16 KB, swizzled

    const int mt = blockIdx.x;                // 0..14 bw-tiles
    const int nt = blockIdx.y;                // 8 e-tiles of 32
    const int k  = blockIdx.z;

    const int lane = tid & 63, wv = tid >> 6;
    const int l15 = lane & 15, quad = lane >> 4;

    // ---- A fragments direct from global fp32, packed to bf16 ----
    const int am = mt * 64 + wv * 16 + l15;   // bw row
    short8 a[8];
    if (am < BW_) {
        const int b = am / W_, w = am - b * W_;
        const float* arow = cFeat + (size_t)(b * S_ + w) * 256;
#pragma unroll
        for (int kt = 0; kt < 8; ++kt) {
            uint4 p = pack8(arow + kt * 32 + quad * 8);
            a[kt] = *(short8*)&p;
        }
    } else {
#pragma unroll
        for (int kt = 0; kt < 8; ++kt) a[kt] = short8{0,0,0,0,0,0,0,0};
    }

    // ---- B staging: 32 rows x 32 chunks = 1024, 4 per thread ----
#pragma unroll
    for (int i = 0; i < 4; ++i) {
        const int flat = i * 256 + tid;
        const int row = flat >> 5, ch = flat & 31;
        const int e = nt * 32 + row;
        uint4 bv = pack8(Wp + ((size_t)(k * 256 + e) * 256 + ch * 8));
        *(uint4*)&Bh[(row * 32 + (ch ^ (row & 7))) * 8] = bv;
    }
    __syncthreads();

    floatx4 acc[2];
#pragma unroll
    for (int n4 = 0; n4 < 2; ++n4) {
        floatx4 c = {0.f, 0.f, 0.f, 0.f};
        const int bn = n4 * 16 + l15;
#pragma unroll
        for (int kt = 0; kt < 8; ++kt) {
            const int ch = kt * 4 + quad;
            short8 bfrag = *(const short8*)&Bh[(bn * 32 + (ch ^ (bn & 7))) * 8];
            c = __builtin_amdgcn_mfma_f32_16x16x32_bf16(a[kt], bfrag, c, 0, 0, 0);
        }
        acc[n4] = c;
    }

#pragma unroll
    for (int n4 = 0; n4 < 2; ++n4) {
        const int e = nt * 32 + n4 * 16 + l15;
#pragma unroll
        for (int r = 0; r < 4; ++r) {
            const int bwo = mt * 64 + wv * 16 + quad * 4 + r;
            if (bwo < BW_)
                locCh[((size_t)k * BW_ + bwo) * 256 + e] = f2bf(acc[n4][r]);
        }
    }
}

// ---------------------------------------------------------------------------
// Stage 2: grid (928, 2). Half-block h scores 64 negatives (h*64..h*64+63);
// h==0 also scores the 12 positives. Emits mergeable LSE partials
// (m, s, mn[, pos]) per (k,bw,h). 1856 small blocks -> ~7 blocks/CU of
// cold-miss streams (round-6 counters: latency-bound, all pipes idle).
// ---------------------------------------------------------------------------
__global__ __launch_bounds__(256) void stage2_mfma(
    const unsigned short* __restrict__ ench,   // (B,S,256) bf16
    const unsigned short* __restrict__ locCh,  // (K,BW,256) bf16
    const int* __restrict__ idxT,              // (BW, 128)
    float* __restrict__ m_arr,                 // (K, BW, 2)
    float* __restrict__ s_arr,                 // (K, BW, 2)
    float* __restrict__ mn_arr,                // (K, BW, 2)
    float* __restrict__ pos_arr)               // (K, BW)
{
    __shared__ int   idxL[80];
    __shared__ float sc[K_ * 68];    // per k: [0..63]=negs, [64]=pos

    const int tid = threadIdx.x;
    const int bw = blockIdx.x;
    const int h  = blockIdx.y;                 // negative half
    const int b = bw / W_, w = bw - b * W_;

    const int lane = tid & 63, wv = tid >> 6;
    const int l15 = lane & 15, quad = lane >> 4;

    // ---- A fragments (12 locC rows) — independent, issue first ----
    const int m = (l15 < K_) ? l15 : (K_ - 1);
    const unsigned short* arow = locCh + ((size_t)m * BW_ + bw) * 256;
    short8 a[8];
#pragma unroll
    for (int kt = 0; kt < 8; ++kt)
        a[kt] = *(const short8*)(arow + kt * 32 + quad * 8);

    // ---- gather rows: 64 negs (coalesced from idxT) + 12 pos (h==0) ----
    if (tid < 64)       idxL[tid] = idxT[bw * 128 + h * 64 + tid];
    else if (tid < 80)  idxL[tid] = b * S_ + ((tid < 76) ? (w + 1 + tid - 64) : w);
    __syncthreads();

    // ---- MFMA: wave wv does neg tile wv; wave 0 (h==0) also pos tile ----
    floatx4 c1 = {0.f, 0.f, 0.f, 0.f};
    {
        const int base = wv * 16 + l15;
        const unsigned short* brow = ench + (size_t)idxL[base] * 256;
#pragma unroll
        for (int kt = 0; kt < 8; ++kt) {
            short8 bfrag = *(const short8*)(brow + kt * 32 + quad * 8);
            c1 = __builtin_amdgcn_mfma_f32_16x16x32_bf16(a[kt], bfrag, c1, 0, 0, 0);
        }
    }
    floatx4 c2 = {0.f, 0.f, 0.f, 0.f};
    if (h == 0 && wv == 0) {
        const unsigned short* brow = ench + (size_t)idxL[64 + l15] * 256;
#pragma unroll
        for (int kt = 0; kt < 8; ++kt) {
            short8 bfrag = *(const short8*)(brow + kt * 32 + quad * 8);
            c2 = __builtin_amdgcn_mfma_f32_16x16x32_bf16(a[kt], bfrag, c2, 0, 0, 0);
        }
    }

    const float inv = 1.0f / 256.0f;
#pragma unroll
    for (int r = 0; r < 4; ++r) {
        const int mm = quad * 4 + r;               // accumulator row = k
        if (mm < K_)
            sc[mm * 68 + wv * 16 + l15] = c1[r] * inv;
    }
    if (h == 0 && wv == 0) {
#pragma unroll
        for (int r = 0; r < 4; ++r) {
            const int mm = quad * 4 + r;
            if (mm < K_ && l15 == mm)              // pos diagonal
                sc[mm * 68 + 64] = c2[r] * inv;
        }
    }
    __syncthreads();

    // ---- per-k partial LSE over this half's 64 negs (+pos for h==0) ----
    for (int k = wv; k < K_; k += 4) {
        const float x = sc[k * 68 + lane];
        float mn = x;
#pragma unroll
        for (int o = 1; o < 64; o <<= 1) mn = fmaxf(mn, __shfl_xor(mn, o, 64));
        float mfull = mn;
        float pos = 0.f;
        if (h == 0) {
            pos = sc[k * 68 + 64];
            mfull = fmaxf(mn, pos);
        }
        float s = __expf(x - mfull);
#pragma unroll
        for (int o = 1; o < 64; o <<= 1) s += __shfl_xor(s, o, 64);
        if (lane == 0) {
            if (h == 0) s += __expf(pos - mfull);
            const int base = (k * BW_ + bw) * 2 + h;
            m_arr[base]  = mfull;
            s_arr[base]  = s;
            mn_arr[base] = mn;
            if (h == 0) pos_arr[k * BW_ + bw] = pos;
        }
    }
}

// ---------------------------------------------------------------------------
// Stage 3: merge the two LSE halves and reduce to the 24 outputs.
// ---------------------------------------------------------------------------
__global__ __launch_bounds__(256) void stage3_reduce(
    const float* __restrict__ m_arr, const float* __restrict__ s_arr,
    const float* __restrict__ mn_arr, const float* __restrict__ pos_arr,
    float* __restrict__ out)
{
    __shared__ float wsum[4];
    const int o = blockIdx.x, tid = threadIdx.x;
    const int k = (o < K_) ? o : (o - K_);
    const bool is_acc = (o >= K_);

    float sacc = 0.f;
    for (int i = tid; i < BW_; i += 256) {
        const int base = (k * BW_ + i) * 2;
        const float pos = pos_arr[k * BW_ + i];
        if (is_acc) {
            const float mn = fmaxf(mn_arr[base], mn_arr[base + 1]);
            sacc += (pos >= mn) ? 1.0f : 0.0f;
        } else {
            const float m0 = m_arr[base], m1 = m_arr[base + 1];
            const float mm = fmaxf(m0, m1);
            const float S = s_arr[base] * __expf(m0 - mm)
                          + s_arr[base + 1] * __expf(m1 - mm);
            sacc += mm + __logf(S) - pos;
        }
    }
#pragma unroll
    for (int off = 1; off < 64; off <<= 1) sacc += __shfl_xor(sacc, off, 64);
    if ((tid & 63) == 0) wsum[tid >> 6] = sacc;
    __syncthreads();
    if (tid == 0)
        out[o] = (wsum[0] + wsum[1] + wsum[2] + wsum[3]) / (float)BW_;
}

// ---------------------------------------------------------------------------
extern "C" void kernel_launch(void* const* d_in, const int* in_sizes, int n_in,
                              void* d_out, int out_size, void* d_ws, size_t ws_size,
                              hipStream_t stream) {
    const float* cFeat    = (const float*)d_in[0];
    const float* enc      = (const float*)d_in[1];
    const float* Wp       = (const float*)d_in[2];
    const int*   batchIdx = (const int*)d_in[3];
    const int*   seqIdx   = (const int*)d_in[4];
    float* out = (float*)d_out;

    unsigned short* ench  = (unsigned short*)d_ws;            // 262144 bf16
    unsigned short* locCh = ench + 262144;                    // K*BW*256 bf16
    int*   idxT   = (int*)(locCh + (size_t)K_ * BW_ * 256);   // 118784 ints
    float* m_arr  = (float*)(idxT + NIDX_);                   // K*BW*2
    float* s_arr  = m_arr  + 2 * K_ * BW_;
    float* mn_arr = s_arr  + 2 * K_ * BW_;
    float* pos_arr= mn_arr + 2 * K_ * BW_;                    // K*BW

    hipLaunchKernelGGL(stage1_mfma, dim3(16, 8, 12), dim3(256), 0, stream,
                       cFeat, Wp, enc, batchIdx, seqIdx, ench, locCh, idxT);
    hipLaunchKernelGGL(stage2_mfma, dim3(BW_, 2), dim3(256), 0, stream,
                       ench, locCh, idxT, m_arr, s_arr, mn_arr, pos_arr);
    hipLaunchKernelGGL(stage3_reduce, dim3(24), dim3(256), 0, stream,
                       m_arr, s_arr, mn_arr, pos_arr, out);
}

// Round 8
// 95.850 us; speedup vs baseline: 1.4487x; 1.0609x over previous
//
#include <hip/hip_runtime.h>
#include <math.h>

#define B_    8
#define S_    128
#define K_    12
#define DAR_  256
#define DENC_ 256
#define NNEG_ 128
#define W_    116          // S - K
#define BW_   928          // B * W
#define NIDX_ 118784       // NNEG * W * B

typedef __attribute__((ext_vector_type(8))) short short8;   // 8 bf16 (4 VGPRs)
typedef __attribute__((ext_vector_type(4))) float floatx4;  // MFMA C/D

static __device__ __forceinline__ unsigned short f2bf(float f) {
    union { float f; unsigned int u; } v; v.f = f;
    return (unsigned short)((v.u + 0x7FFFu + ((v.u >> 16) & 1u)) >> 16);  // RNE
}

static __device__ __forceinline__ uint4 pack2(float4 v0, float4 v1) {
    uint4 o;
    o.x = f2bf(v0.x) | ((unsigned)f2bf(v0.y) << 16);
    o.y = f2bf(v0.z) | ((unsigned)f2bf(v0.w) << 16);
    o.z = f2bf(v1.x) | ((unsigned)f2bf(v1.y) << 16);
    o.w = f2bf(v1.z) | ((unsigned)f2bf(v1.w) << 16);
    return o;
}

// ---------------------------------------------------------------------------
// Stage 1: grid (16,4,12). x<15: 64x64 MFMA tile. x==15: aux (cast enc->bf16
// + idxT precompute). ALL global loads explicitly batched into register
// arrays before use; __launch_bounds__(256,2) lifts the VGPR cap so the
// compiler keeps them in flight (round-6 showed VGPR=56 -> serialized loads).
// ---------------------------------------------------------------------------
__global__ __launch_bounds__(256, 2) void stage1_mfma(
    const float* __restrict__ cFeat,   // (B,S,256) fp32
    const float* __restrict__ Wp,      // (K,256,256) fp32
    const float* __restrict__ enc,     // (B,S,256) fp32
    const int* __restrict__ batchIdx,
    const int* __restrict__ seqIdx,
    unsigned short* __restrict__ ench, // (B,S,256) bf16 out
    unsigned short* __restrict__ locCh,// (K,BW,256) bf16 out
    int* __restrict__ idxT)            // (BW, 128) gather rows
{
    const int tid = threadIdx.x;

    if (blockIdx.x == 15) {            // ---- aux: cast + idx table ----
        const int ab = blockIdx.z * 4 + blockIdx.y;        // 0..47
        for (int c = ab * 256 + tid; c < 32768; c += 48 * 256) {
            float4 v0 = *(const float4*)(enc + c * 8);
            float4 v1 = *(const float4*)(enc + c * 8 + 4);
            *(uint4*)(ench + c * 8) = pack2(v0, v1);
        }
        for (int j = ab * 256 + tid; j < NIDX_; j += 48 * 256) {
            const int n = j & 127, bw = j >> 7;
            const int b = bw / W_, w = bw - b * W_;
            const int ii = (b * NNEG_ + n) * W_ + w;
            const int bi = batchIdx[ii];
            int si = seqIdx[ii] + w;               // < 243
            if (si >= S_) si -= S_;
            idxT[j] = bi * S_ + si;
        }
        return;
    }

    __shared__ unsigned short Bh[64 * 256];   // 32 KB, swizzled

    const int mt = blockIdx.x;                // 0..14 bw-tiles
    const int nt = blockIdx.y;                // 4 e-tiles of 64
    const int k  = blockIdx.z;

    const int lane = tid & 63, wv = tid >> 6;
    const int l15 = lane & 15, quad = lane >> 4;

    // ---- A: batch all 16 fp32 float4 loads, then pack ----
    const int am = mt * 64 + wv * 16 + l15;   // bw row
    float4 af[8][2];
    const bool aval = (am < BW_);
    {
        const int bb = aval ? (am / W_) : 0;
        const int ww = aval ? (am - bb * W_) : 0;
        const float* arow = cFeat + (size_t)(bb * S_ + ww) * 256;
#pragma unroll
        for (int kt = 0; kt < 8; ++kt) {
            af[kt][0] = *(const float4*)(arow + kt * 32 + quad * 8);
            af[kt][1] = *(const float4*)(arow + kt * 32 + quad * 8 + 4);
        }
    }

    // ---- B staging: batch all 16 fp32 float4 loads, then pack+write ----
    float4 bf[8][2];
#pragma unroll
    for (int i = 0; i < 8; ++i) {
        const int flat = i * 256 + tid;        // 8-float segment id
        const int row = flat >> 5, ch = flat & 31;
        const float* p = Wp + ((size_t)(k * 256 + nt * 64 + row) * 256 + ch * 8);
        bf[i][0] = *(const float4*)p;
        bf[i][1] = *(const float4*)(p + 4);
    }

    short8 a[8];
#pragma unroll
    for (int kt = 0; kt < 8; ++kt) {
        uint4 p = pack2(af[kt][0], af[kt][1]);
        if (!aval) p = make_uint4(0, 0, 0, 0);
        a[kt] = *(short8*)&p;
    }
#pragma unroll
    for (int i = 0; i < 8; ++i) {
        const int flat = i * 256 + tid;
        const int row = flat >> 5, ch = flat & 31;
        *(uint4*)&Bh[(row * 32 + (ch ^ (row & 7))) * 8] = pack2(bf[i][0], bf[i][1]);
    }
    __syncthreads();

    floatx4 acc[4];
#pragma unroll
    for (int n4 = 0; n4 < 4; ++n4) {
        floatx4 c = {0.f, 0.f, 0.f, 0.f};
        const int bn = n4 * 16 + l15;
#pragma unroll
        for (int kt = 0; kt < 8; ++kt) {
            const int ch = kt * 4 + quad;
            short8 bfrag = *(const short8*)&Bh[(bn * 32 + (ch ^ (bn & 7))) * 8];
            c = __builtin_amdgcn_mfma_f32_16x16x32_bf16(a[kt], bfrag, c, 0, 0, 0);
        }
        acc[n4] = c;
    }

    // D: col(e)=l15, row(bw)=quad*4+r within subtile
#pragma unroll
    for (int n4 = 0; n4 < 4; ++n4) {
        const int e = nt * 64 + n4 * 16 + l15;
#pragma unroll
        for (int r = 0; r < 4; ++r) {
            const int bwo = mt * 64 + wv * 16 + quad * 4 + r;
            if (bwo < BW_)
                locCh[((size_t)k * BW_ + bwo) * 256 + e] = f2bf(acc[n4][r]);
        }
    }
}

// ---------------------------------------------------------------------------
// Stage 2: one block per (b,w). A-frags (8 loads) and ALL 24 B-frags batched
// in registers (~130 VGPRs live) so each wave keeps ~30 lines in flight.
// ---------------------------------------------------------------------------
__global__ __launch_bounds__(256, 2) void stage2_mfma(
    const unsigned short* __restrict__ ench,   // (B,S,256) bf16
    const unsigned short* __restrict__ locCh,  // (K,BW,256) bf16
    const int* __restrict__ idxT,              // (BW, 128)
    float* __restrict__ part)                  // (2K, BW)
{
    __shared__ int   idxL[144];
    __shared__ float sc[K_ * 132];   // [0..127]=neg, [128]=pos

    const int tid = threadIdx.x;
    const int bw = blockIdx.x;
    const int b = bw / W_, w = bw - b * W_;

    const int lane = tid & 63, wv = tid >> 6;
    const int l15 = lane & 15, quad = lane >> 4;

    // ---- A fragments: 8 batched loads ----
    const int m = (l15 < K_) ? l15 : (K_ - 1);
    const unsigned short* arow = locCh + ((size_t)m * BW_ + bw) * 256;
    short8 a[8];
#pragma unroll
    for (int kt = 0; kt < 8; ++kt)
        a[kt] = *(const short8*)(arow + kt * 32 + quad * 8);

    // ---- gather row indices ----
    if (tid < 128)      idxL[tid] = idxT[bw * 128 + tid];
    else if (tid < 140) idxL[tid] = b * S_ + w + 1 + (tid - 128);   // positives
    else if (tid < 144) idxL[tid] = b * S_ + w;                     // pad
    __syncthreads();

    // ---- batch ALL 24 B-fragment loads (3 tiles/wave x 8 kt) ----
    short8 bfr[3][8];
#pragma unroll
    for (int u = 0; u < 3; ++u) {
        const int t = wv + u * 4;              // 0..11, tiles >=9 unused
        const int n = t * 16 + l15;
        const int nn = (t < 9) ? ((n < 140) ? n : 128) : 128;
        const unsigned short* brow = ench + (size_t)idxL[nn] * 256;
#pragma unroll
        for (int kt = 0; kt < 8; ++kt)
            bfr[u][kt] = *(const short8*)(brow + kt * 32 + quad * 8);
    }

    floatx4 accT[3];
#pragma unroll
    for (int u = 0; u < 3; ++u) {
        floatx4 c = {0.f, 0.f, 0.f, 0.f};
#pragma unroll
        for (int kt = 0; kt < 8; ++kt)
            c = __builtin_amdgcn_mfma_f32_16x16x32_bf16(a[kt], bfr[u][kt], c, 0, 0, 0);
        accT[u] = c;
    }

    const float inv = 1.0f / 256.0f;
#pragma unroll
    for (int u = 0; u < 3; ++u) {
        const int t = wv + u * 4;
        if (t < 9) {
#pragma unroll
            for (int r = 0; r < 4; ++r) {
                const int mm = quad * 4 + r;       // accumulator row = k
                if (mm < K_) {
                    const float val = accT[u][r] * inv;
                    if (t < 8)           sc[mm * 132 + t * 16 + l15] = val;  // neg
                    else if (l15 == mm)  sc[mm * 132 + 128] = val;           // pos
                }
            }
        }
    }
    __syncthreads();

    // ---- LSE + acc per k (wave wv: k = wv, wv+4, wv+8) ----
    for (int k = wv; k < K_; k += 4) {
        const float x0  = sc[k * 132 + lane];
        const float x1  = sc[k * 132 + 64 + lane];
        const float pos = sc[k * 132 + 128];
        float mn = fmaxf(x0, x1);
#pragma unroll
        for (int o = 1; o < 64; o <<= 1) mn = fmaxf(mn, __shfl_xor(mn, o, 64));
        const float m2 = fmaxf(mn, pos);
        float s = __expf(x0 - m2) + __expf(x1 - m2);
#pragma unroll
        for (int o = 1; o < 64; o <<= 1) s += __shfl_xor(s, o, 64);
        if (lane == 0) {
            const float lse = m2 + __logf(s + __expf(pos - m2));
            part[k * BW_ + bw]        = lse - pos;
            part[(K_ + k) * BW_ + bw] = (pos >= mn) ? 1.0f : 0.0f;
        }
    }
}

// ---------------------------------------------------------------------------
// Stage 3: reduce (2K, BW) partials to the 24 outputs.
// ---------------------------------------------------------------------------
__global__ __launch_bounds__(256) void stage3_reduce(
    const float* __restrict__ part, float* __restrict__ out)
{
    __shared__ float wsum[4];
    const int o = blockIdx.x, tid = threadIdx.x;
    float s = 0.f;
    for (int i = tid; i < BW_; i += 256) s += part[o * BW_ + i];
#pragma unroll
    for (int off = 1; off < 64; off <<= 1) s += __shfl_xor(s, off, 64);
    if ((tid & 63) == 0) wsum[tid >> 6] = s;
    __syncthreads();
    if (tid == 0)
        out[o] = (wsum[0] + wsum[1] + wsum[2] + wsum[3]) / (float)BW_;
}

// ---------------------------------------------------------------------------
extern "C" void kernel_launch(void* const* d_in, const int* in_sizes, int n_in,
                              void* d_out, int out_size, void* d_ws, size_t ws_size,
                              hipStream_t stream) {
    const float* cFeat    = (const float*)d_in[0];
    const float* enc      = (const float*)d_in[1];
    const float* Wp       = (const float*)d_in[2];
    const int*   batchIdx = (const int*)d_in[3];
    const int*   seqIdx   = (const int*)d_in[4];
    float* out = (float*)d_out;

    unsigned short* ench  = (unsigned short*)d_ws;            // 262144 bf16
    unsigned short* locCh = ench + 262144;                    // K*BW*256 bf16
    int*   idxT = (int*)(locCh + (size_t)K_ * BW_ * 256);     // 118784 ints
    float* part = (float*)(idxT + NIDX_);                     // (2K, BW)

    hipLaunchKernelGGL(stage1_mfma, dim3(16, 4, 12), dim3(256), 0, stream,
                       cFeat, Wp, enc, batchIdx, seqIdx, ench, locCh, idxT);
    hipLaunchKernelGGL(stage2_mfma, dim3(BW_), dim3(256), 0, stream,
                       ench, locCh, idxT, part);
    hipLaunchKernelGGL(stage3_reduce, dim3(24), dim3(256), 0, stream,
                       part, out);
}